// Round 8
// baseline (132.160 us; speedup 1.0000x reference)
//
#include <hip/hip_runtime.h>

// BPS pipeline v8: d_out = f32[2L]: [0,L) = real(out), [L,2L) = ph (= unwrap(ang)/4).
// R5-R7 proved: chunk0 = flat[0:L] vs real(out) [passes with re-plane], chunk1 = flat[L:2L].

#define LN   65536
#define PI_F 3.14159265358979323846f
#define TWO_PI_F 6.2831853071795864769f

__constant__ float v8_tri_pad[136] = {
    0,0,0,
    1,2,3,4,5,6,7,8,9,10,11,12,13,14,15,16,17,18,19,20,21,22,23,24,25,26,27,28,
    29,30,31,32,33,34,35,36,37,38,39,40,41,42,43,44,45,46,47,48,49,50,51,52,53,
    54,55,56,57,58,59,60,61,62,63,64,65,
    64,63,62,61,60,59,58,57,56,55,54,53,52,51,50,49,48,47,46,45,44,43,42,41,40,
    39,38,37,36,35,34,33,32,31,30,29,28,27,26,25,24,23,22,21,20,19,18,17,16,15,
    14,13,12,11,10,9,8,7,6,5,4,3,2,1,
    0,0,0,0
};

#define ACC4V(A, W) do { float w_ = (W); \
    A.x = fmaf(w_, v.x, A.x); A.y = fmaf(w_, v.y, A.y); \
    A.z = fmaf(w_, v.z, A.z); A.w = fmaf(w_, v.w, A.w); } while (0)

// Stage 1: per block of 64 outputs: dist tile (64-halo) -> 129-tap conv -> softmin -> ang
__global__ __launch_bounds__(256) void v8_stage_ang(const float* __restrict__ xr,
                                                    const float* __restrict__ xi,
                                                    const float* __restrict__ temp,
                                                    float* __restrict__ ang_out) {
    __shared__ __align__(16) float sbuf[192 * 64];  // dist tile; then mvg (row stride 68)
    __shared__ float s4v[64], c4v[64];              // sin/cos of 4*angles

    const int t  = threadIdx.x;
    const int l0 = blockIdx.x * 64;

    if (t < 64) {
        float a4 = (float)t * (PI_F / 32.0f) - PI_F;   // 4*angles[m]
        float s, c; sincosf(a4, &s, &c);
        s4v[t] = s; c4v[t] = c;
    }

    // Phase 1: dist staging via separable nearest-64QAM quantization
    // (value-equivalent to brute-force reference form: R3 == R4 bit-identical)
    {
        const int m = t & 63;
        const float am = (float)m * (PI_F / 128.0f) - (PI_F * 0.25f);
        float sm, cm; sincosf(am, &sm, &cm);
        const float SQ = 6.4807406984078602f;   // sqrt(42)
        #pragma unroll 4
        for (int j = 0; j < 48; ++j) {
            int li = (t >> 6) + 4 * j;
            int gl = l0 - 64 + li;
            float d = 0.0f;
            if ((unsigned)gl < (unsigned)LN) {
                float a = xr[gl], b = xi[gl];
                float Er = a * cm - b * sm;
                float Ei = a * sm + b * cm;
                float tr = Er * SQ, ti = Ei * SQ;
                float rr = fminf(fmaxf(rintf((tr + 7.0f) * 0.5f), 0.0f), 7.0f);
                float ri = fminf(fmaxf(rintf((ti + 7.0f) * 0.5f), 0.0f), 7.0f);
                float dr = tr - (2.0f * rr - 7.0f);
                float di = ti - (2.0f * ri - 7.0f);
                d = (dr * dr + di * di) * (1.0f / 42.0f);
            }
            sbuf[li * 64 + m] = d;
        }
    }
    __syncthreads();

    // Phase 2: 129-tap conv, 4 consecutive rows/thread
    const int m4  = t & 15;
    const int lob = (t >> 4) * 4;
    float4 a0 = make_float4(0,0,0,0), a1 = a0, a2 = a0, a3 = a0;
    {
        const float4* sd4 = (const float4*)sbuf;
        #pragma unroll 4
        for (int i = 0; i < 132; ++i) {
            float4 v = sd4[(lob + i) * 16 + m4];
            ACC4V(a0, v8_tri_pad[i + 3]);
            ACC4V(a1, v8_tri_pad[i + 2]);
            ACC4V(a2, v8_tri_pad[i + 1]);
            ACC4V(a3, v8_tri_pad[i + 0]);
        }
    }
    __syncthreads();
    {
        float4* sm4 = (float4*)sbuf;   // mvg rows, stride 68 floats
        sm4[(lob + 0) * 17 + m4] = a0;
        sm4[(lob + 1) * 17 + m4] = a1;
        sm4[(lob + 2) * 17 + m4] = a2;
        sm4[(lob + 3) * 17 + m4] = a3;
    }
    __syncthreads();

    // Phase 3: row-normalize + softmin + atan2 (4 lanes per row)
    {
        const float T = temp[0];
        const int lane = t & 63;
        const int sub  = lane & 3;
        const int l    = (t >> 6) * 16 + (lane >> 2);
        const int mb   = sub * 16;

        float rs = 0.0f, mn = 3.4e38f;
        #pragma unroll
        for (int i = 0; i < 16; ++i) {
            float v = sbuf[l * 68 + mb + i];
            rs += v; mn = fminf(mn, v);
        }
        rs += __shfl_xor(rs, 1, 64); rs += __shfl_xor(rs, 2, 64);
        mn = fminf(mn, __shfl_xor(mn, 1, 64)); mn = fminf(mn, __shfl_xor(mn, 2, 64));

        float inv = 1.0f / (rs * T);
        float ss = 0.0f, sc = 0.0f;
        #pragma unroll
        for (int i = 0; i < 16; ++i) {
            int mm = mb + i;
            float v = sbuf[l * 68 + mm];
            float e = __expf((mn - v) * inv);
            ss = fmaf(e, s4v[mm], ss);
            sc = fmaf(e, c4v[mm], sc);
        }
        ss += __shfl_xor(ss, 1, 64); ss += __shfl_xor(ss, 2, 64);
        sc += __shfl_xor(sc, 1, 64); sc += __shfl_xor(sc, 2, 64);
        if (sub == 0) ang_out[l0 + l] = atan2f(ss, sc);
    }
}

// Stage 2: unwrap as integer prefix scan (single 1024-thread block)
__global__ __launch_bounds__(1024) void v8_stage_scan(const float* __restrict__ ang,
                                                      int* __restrict__ kbuf) {
    __shared__ int tsum[1024];
    const int t = threadIdx.x;
    const int base = t * 64;

    float prev = (t == 0) ? 0.0f : ang[base - 1];
    int s = 0;
    {
        float p = prev;
        for (int i = 0; i < 64; ++i) {
            float a = ang[base + i];
            if (base + i > 0) {
                float dd = a - p;
                s += (dd < -PI_F) ? 1 : ((dd > PI_F) ? -1 : 0);
            }
            p = a;
        }
    }
    tsum[t] = s;
    __syncthreads();
    for (int off = 1; off < 1024; off <<= 1) {
        int add = (t >= off) ? tsum[t - off] : 0;
        __syncthreads();
        tsum[t] += add;
        __syncthreads();
    }
    int k = tsum[t] - s;
    {
        float p = prev;
        for (int i = 0; i < 64; ++i) {
            float a = ang[base + i];
            if (base + i > 0) {
                float dd = a - p;
                k += (dd < -PI_F) ? 1 : ((dd > PI_F) ? -1 : 0);
            }
            p = a;
            kbuf[base + i] = k;
        }
    }
}

// Stage 3: d_out (f32, 2L elements): [0,L) = real(x*exp(i*ph)), [L,2L) = ph = (ang+2pi*k)/4.
__global__ __launch_bounds__(256) void v8_stage_out(const float* __restrict__ xr,
                                                    const float* __restrict__ xi,
                                                    const float* __restrict__ ang,
                                                    const int* __restrict__ kbuf,
                                                    float* __restrict__ out_base) {
    int l = blockIdx.x * 256 + threadIdx.x;
    float ph = (ang[l] + TWO_PI_F * (float)kbuf[l]) * 0.25f;
    float s, c; sincosf(ph, &s, &c);
    float a = xr[l], b = xi[l];
    out_base[l]      = a * c - b * s;   // real(out)
    out_base[LN + l] = ph;              // ph channel
}

extern "C" void kernel_launch(void* const* d_in, const int* in_sizes, int n_in,
                              void* d_out, int out_size, void* d_ws, size_t ws_size,
                              hipStream_t stream) {
    (void)in_sizes; (void)n_in; (void)out_size; (void)ws_size;
    const float* xr   = (const float*)d_in[0];
    const float* xi   = (const float*)d_in[1];
    const float* temp = (const float*)d_in[5];

    float* ang = (float*)d_ws;
    int*   kb  = (int*)((char*)d_ws + LN * sizeof(float));

    v8_stage_ang <<<LN / 64, 256, 0, stream>>>(xr, xi, temp, ang);
    v8_stage_scan<<<1, 1024, 0, stream>>>(ang, kb);
    v8_stage_out <<<LN / 256, 256, 0, stream>>>(xr, xi, ang, kb, (float*)d_out);
}

// Round 9
// 98.901 us; speedup vs baseline: 1.3363x; 1.3363x over previous
//
#include <hip/hip_runtime.h>

// BPS pipeline v9: PASSING semantics from v8; serial 1-block scan replaced by
// hierarchical coalesced scan (S1 local + offset reduce fused into stage_out).
// d_out = f32[2L]: [0,L) = real(x*exp(i*ph)), [L,2L) = ph = unwrap(ang)/4.

#define LN   65536
#define PI_F 3.14159265358979323846f
#define TWO_PI_F 6.2831853071795864769f

#define CORR(dd) (((dd) < -PI_F) ? 1 : (((dd) > PI_F) ? -1 : 0))

__constant__ float v9_tri_pad[136] = {
    0,0,0,
    1,2,3,4,5,6,7,8,9,10,11,12,13,14,15,16,17,18,19,20,21,22,23,24,25,26,27,28,
    29,30,31,32,33,34,35,36,37,38,39,40,41,42,43,44,45,46,47,48,49,50,51,52,53,
    54,55,56,57,58,59,60,61,62,63,64,65,
    64,63,62,61,60,59,58,57,56,55,54,53,52,51,50,49,48,47,46,45,44,43,42,41,40,
    39,38,37,36,35,34,33,32,31,30,29,28,27,26,25,24,23,22,21,20,19,18,17,16,15,
    14,13,12,11,10,9,8,7,6,5,4,3,2,1,
    0,0,0,0
};

#define ACC4V(A, W) do { float w_ = (W); \
    A.x = fmaf(w_, v.x, A.x); A.y = fmaf(w_, v.y, A.y); \
    A.z = fmaf(w_, v.z, A.z); A.w = fmaf(w_, v.w, A.w); } while (0)

// Stage 1: per block of 64 outputs: dist tile (64-halo) -> 129-tap conv -> softmin -> ang
__global__ __launch_bounds__(256) void v9_stage_ang(const float* __restrict__ xr,
                                                    const float* __restrict__ xi,
                                                    const float* __restrict__ temp,
                                                    float* __restrict__ ang_out) {
    __shared__ __align__(16) float sbuf[192 * 64];  // dist tile; then mvg (row stride 68)
    __shared__ float s4v[64], c4v[64];              // sin/cos of 4*angles

    const int t  = threadIdx.x;
    const int l0 = blockIdx.x * 64;

    if (t < 64) {
        float a4 = (float)t * (PI_F / 32.0f) - PI_F;   // 4*angles[m]
        float s, c; sincosf(a4, &s, &c);
        s4v[t] = s; c4v[t] = c;
    }

    // Phase 1: dist staging via separable nearest-64QAM quantization
    {
        const int m = t & 63;
        const float am = (float)m * (PI_F / 128.0f) - (PI_F * 0.25f);
        float sm, cm; sincosf(am, &sm, &cm);
        const float SQ = 6.4807406984078602f;   // sqrt(42)
        #pragma unroll 4
        for (int j = 0; j < 48; ++j) {
            int li = (t >> 6) + 4 * j;
            int gl = l0 - 64 + li;
            float d = 0.0f;
            if ((unsigned)gl < (unsigned)LN) {
                float a = xr[gl], b = xi[gl];
                float Er = a * cm - b * sm;
                float Ei = a * sm + b * cm;
                float tr = Er * SQ, ti = Ei * SQ;
                float rr = fminf(fmaxf(rintf((tr + 7.0f) * 0.5f), 0.0f), 7.0f);
                float ri = fminf(fmaxf(rintf((ti + 7.0f) * 0.5f), 0.0f), 7.0f);
                float dr = tr - (2.0f * rr - 7.0f);
                float di = ti - (2.0f * ri - 7.0f);
                d = (dr * dr + di * di) * (1.0f / 42.0f);
            }
            sbuf[li * 64 + m] = d;
        }
    }
    __syncthreads();

    // Phase 2: 129-tap conv, 4 consecutive rows/thread
    const int m4  = t & 15;
    const int lob = (t >> 4) * 4;
    float4 a0 = make_float4(0,0,0,0), a1 = a0, a2 = a0, a3 = a0;
    {
        const float4* sd4 = (const float4*)sbuf;
        #pragma unroll 4
        for (int i = 0; i < 132; ++i) {
            float4 v = sd4[(lob + i) * 16 + m4];
            ACC4V(a0, v9_tri_pad[i + 3]);
            ACC4V(a1, v9_tri_pad[i + 2]);
            ACC4V(a2, v9_tri_pad[i + 1]);
            ACC4V(a3, v9_tri_pad[i + 0]);
        }
    }
    __syncthreads();
    {
        float4* sm4 = (float4*)sbuf;   // mvg rows, stride 68 floats
        sm4[(lob + 0) * 17 + m4] = a0;
        sm4[(lob + 1) * 17 + m4] = a1;
        sm4[(lob + 2) * 17 + m4] = a2;
        sm4[(lob + 3) * 17 + m4] = a3;
    }
    __syncthreads();

    // Phase 3: row-normalize + softmin + atan2 (4 lanes per row)
    {
        const float T = temp[0];
        const int lane = t & 63;
        const int sub  = lane & 3;
        const int l    = (t >> 6) * 16 + (lane >> 2);
        const int mb   = sub * 16;

        float rs = 0.0f, mn = 3.4e38f;
        #pragma unroll
        for (int i = 0; i < 16; ++i) {
            float v = sbuf[l * 68 + mb + i];
            rs += v; mn = fminf(mn, v);
        }
        rs += __shfl_xor(rs, 1, 64); rs += __shfl_xor(rs, 2, 64);
        mn = fminf(mn, __shfl_xor(mn, 1, 64)); mn = fminf(mn, __shfl_xor(mn, 2, 64));

        float inv = 1.0f / (rs * T);
        float ss = 0.0f, sc = 0.0f;
        #pragma unroll
        for (int i = 0; i < 16; ++i) {
            int mm = mb + i;
            float v = sbuf[l * 68 + mm];
            float e = __expf((mn - v) * inv);
            ss = fmaf(e, s4v[mm], ss);
            sc = fmaf(e, c4v[mm], sc);
        }
        ss += __shfl_xor(ss, 1, 64); ss += __shfl_xor(ss, 2, 64);
        sc += __shfl_xor(sc, 1, 64); sc += __shfl_xor(sc, 2, 64);
        if (sub == 0) ang_out[l0 + l] = atan2f(ss, sc);
    }
}

// Stage 2 (S1): coalesced block-local correction scan.
// 64 blocks x 256 threads x 4 elements. klocal[i] = inclusive sum of corrections
// within the block's 1024-element chunk; bsum[b] = chunk total.
__global__ __launch_bounds__(256) void v9_scan_local(const float* __restrict__ ang,
                                                     int* __restrict__ klocal,
                                                     int* __restrict__ bsum) {
    __shared__ int wtot[4];
    const int t = threadIdx.x;
    const int b = blockIdx.x;
    const int e = b * 256 + t;        // element-quad index
    const int i4 = e * 4;

    float4 a = *(const float4*)(ang + i4);
    float prev = (i4 == 0) ? 0.0f : ang[i4 - 1];   // i4==0: |a.x|<=pi -> corr 0 anyway

    int s0 = CORR(a.x - prev);
    int s1 = CORR(a.y - a.x);
    int s2 = CORR(a.z - a.y);
    int s3 = CORR(a.w - a.z);
    int k0 = s0, k1 = k0 + s1, k2 = k1 + s2, k3 = k2 + s3;

    const int lane = t & 63, wv = t >> 6;
    int scan = k3;                    // thread total
    #pragma unroll
    for (int off = 1; off < 64; off <<= 1) {
        int v = __shfl_up(scan, off, 64);
        if (lane >= off) scan += v;
    }
    if (lane == 63) wtot[wv] = scan;
    __syncthreads();
    int woff = 0;
    #pragma unroll
    for (int j = 0; j < 3; ++j) if (j < wv) woff += wtot[j];
    const int excl = woff + scan - k3;   // exclusive prefix for this thread in block

    ((int4*)klocal)[e] = make_int4(excl + k0, excl + k1, excl + k2, excl + k3);
    if (t == 255) bsum[b] = woff + scan;
}

// Stage 3: k = klocal + chunk offset (wave-reduced from bsum); ph=(ang+2pi k)/4;
// d_out: [0,L) = real(x*exp(i*ph)), [L,2L) = ph.
__global__ __launch_bounds__(512) void v9_stage_out(const float* __restrict__ xr,
                                                    const float* __restrict__ xi,
                                                    const float* __restrict__ ang,
                                                    const int* __restrict__ klocal,
                                                    const int* __restrict__ bsum,
                                                    float* __restrict__ out_base) {
    __shared__ int s_boff;
    const int t = threadIdx.x;
    const int b = blockIdx.x;
    const int chunk = b >> 1;         // 512-thread block spans half a 1024-chunk

    if (t < 64) {
        int v = (t < chunk) ? bsum[t] : 0;
        #pragma unroll
        for (int off = 1; off < 64; off <<= 1) v += __shfl_xor(v, off, 64);
        if (t == 0) s_boff = v;
    }
    __syncthreads();

    const int l = b * 512 + t;
    float ph = (ang[l] + TWO_PI_F * (float)(klocal[l] + s_boff)) * 0.25f;
    float s, c; sincosf(ph, &s, &c);
    float a = xr[l], bb = xi[l];
    out_base[l]      = a * c - bb * s;   // real(out)
    out_base[LN + l] = ph;               // ph channel
}

extern "C" void kernel_launch(void* const* d_in, const int* in_sizes, int n_in,
                              void* d_out, int out_size, void* d_ws, size_t ws_size,
                              hipStream_t stream) {
    (void)in_sizes; (void)n_in; (void)out_size; (void)ws_size;
    const float* xr   = (const float*)d_in[0];
    const float* xi   = (const float*)d_in[1];
    const float* temp = (const float*)d_in[5];

    float* ang    = (float*)d_ws;                                  // L f32
    int*   klocal = (int*)((char*)d_ws + LN * sizeof(float));      // L i32
    int*   bsum   = (int*)((char*)d_ws + 2 * LN * sizeof(float));  // 64 i32

    v9_stage_ang <<<LN / 64, 256, 0, stream>>>(xr, xi, temp, ang);
    v9_scan_local<<<64, 256, 0, stream>>>(ang, klocal, bsum);
    v9_stage_out <<<LN / 512, 512, 0, stream>>>(xr, xi, ang, klocal, bsum, (float*)d_out);
}

// Round 10
// 86.031 us; speedup vs baseline: 1.5362x; 1.1496x over previous
//
#include <hip/hip_runtime.h>

// BPS pipeline v10: v9 semantics; stage_ang conv rewritten as box65*box65
// double-prefix (tri filter [1..65..1] = box ** box), register-resident dist.
// d_out = f32[2L]: [0,L) = real(x*exp(i*ph)), [L,2L) = ph = unwrap(ang)/4.

#define LN   65536
#define PI_F 3.14159265358979323846f
#define TWO_PI_F 6.2831853071795864769f

#define CORR(dd) (((dd) < -PI_F) ? 1 : (((dd) > PI_F) ? -1 : 0))

// Stage 1: per block of 64 outputs. Thread (m = t&63, seg = t>>6) owns rows
// seg*48..seg*48+47 of the 192-row (64-halo) dist tile for column m.
// dist -> P1 (prefix along l) -> box1 = P1 diff -> Q (prefix of box1) -> mvg = Q diff.
__global__ __launch_bounds__(256) void v10_stage_ang(const float* __restrict__ xr,
                                                     const float* __restrict__ xi,
                                                     const float* __restrict__ temp,
                                                     float* __restrict__ ang_out) {
    __shared__ float P1[64 * 193];   // P1[m][li], li=0..191 (pad 193: 2-way banks); reused as Q[m][131]
    __shared__ float tot1[64 * 5];   // per-(m,seg) totals, pass 1
    __shared__ float tot2[64 * 5];   // pass 2
    __shared__ float s4v[64], c4v[64];

    const int t   = threadIdx.x;
    const int l0  = blockIdx.x * 64;
    const int m   = t & 63;
    const int seg = t >> 6;          // == wave id; uniform per wave

    if (t < 64) {
        float a4 = (float)t * (PI_F / 32.0f) - PI_F;   // 4*angles[m]
        float s, c; sincosf(a4, &s, &c);
        s4v[t] = s; c4v[t] = c;
    }

    // ---- Phase 1: dist (separable nearest-64QAM quantization) + register prefix ----
    {
        const float am = (float)m * (PI_F / 128.0f) - (PI_F * 0.25f);
        float sm, cm; sincosf(am, &sm, &cm);
        const float SQ = 6.4807406984078602f;   // sqrt(42)
        const float cq = cm * SQ, sq = sm * SQ; // fold constellation scale into rotation
        float pr[48];
        float p = 0.0f;
        #pragma unroll
        for (int i = 0; i < 48; ++i) {
            int li = seg * 48 + i;
            int gl = l0 - 64 + li;
            float d = 0.0f;                     // zero padding outside [0,L)
            if ((unsigned)gl < (unsigned)LN) {
                float a = xr[gl], b = xi[gl];
                float tr = a * cq - b * sq;     // sqrt42 * Re(x e^{i angle})
                float ti = a * sq + b * cq;
                float rr = fminf(fmaxf(rintf(fmaf(tr, 0.5f, 3.5f)), 0.0f), 7.0f);
                float ri = fminf(fmaxf(rintf(fmaf(ti, 0.5f, 3.5f)), 0.0f), 7.0f);
                float dr = fmaf(-2.0f, rr, tr + 7.0f);
                float di = fmaf(-2.0f, ri, ti + 7.0f);
                d = fmaf(dr, dr, di * di) * (1.0f / 42.0f);
            }
            p += d;
            pr[i] = p;
        }
        tot1[m * 5 + seg] = p;
        __syncthreads();
        float off = 0.0f;
        #pragma unroll
        for (int s = 0; s < 3; ++s) if (s < seg) off += tot1[m * 5 + s];
        #pragma unroll
        for (int i = 0; i < 48; ++i) P1[m * 193 + seg * 48 + i] = pr[i] + off;
    }
    __syncthreads();

    // ---- Phase 2: box1[li]=P1[li+32]-P1[li-33] for li=31..159 (j=li-31: 0..128),
    //      register prefix -> Q[m][j] (reuses P1 storage after all reads complete) ----
    const int jn = (seg < 3) ? 33 : 30;   // segs 0..2: 33 each, seg 3: 30 (129 total)
    const int j0 = seg * 33;
    {
        float q[33];
        float p2 = 0.0f;
        #pragma unroll
        for (int i = 0; i < 33; ++i) {
            if (i < jn) {
                int j = j0 + i;
                float hi = P1[m * 193 + 63 + j];
                float lo = (j >= 2) ? P1[m * 193 + j - 2] : 0.0f;
                p2 += hi - lo;
                q[i] = p2;
            }
        }
        tot2[m * 5 + seg] = p2;
        __syncthreads();                   // all P1 reads done; safe to overwrite as Q
        float off2 = 0.0f;
        #pragma unroll
        for (int s = 0; s < 3; ++s) if (s < seg) off2 += tot2[m * 5 + s];
        float* Q = P1;                     // Q[m][j] at m*131 + j (pad 131: 2-way banks)
        #pragma unroll
        for (int i = 0; i < 33; ++i) if (i < jn) Q[m * 131 + j0 + i] = q[i] + off2;
    }
    __syncthreads();

    // ---- Phase 3: mvg[r][mm] = Q[mm][r+65]-Q[mm][r]; row-normalize + softmin + atan2 ----
    {
        const float* Q = P1;
        const float T = temp[0];
        const int lane = t & 63;
        const int sub  = lane & 3;          // 4 lanes share one output row
        const int r    = (t >> 6) * 16 + (lane >> 2);   // 0..63
        const int mb   = sub * 16;

        float v[16];
        float rs = 0.0f, mn = 3.4e38f;
        #pragma unroll
        for (int i = 0; i < 16; ++i) {
            int mm = mb + i;
            float vv = Q[mm * 131 + r + 65] - Q[mm * 131 + r];
            v[i] = vv; rs += vv; mn = fminf(mn, vv);
        }
        rs += __shfl_xor(rs, 1, 64); rs += __shfl_xor(rs, 2, 64);
        mn = fminf(mn, __shfl_xor(mn, 1, 64)); mn = fminf(mn, __shfl_xor(mn, 2, 64));

        // softmax(-mvg_norm/T) weights exp((mn-v)/(rs*T)); denominator cancels in atan2
        float inv = 1.0f / (rs * T);
        float ss = 0.0f, sc = 0.0f;
        #pragma unroll
        for (int i = 0; i < 16; ++i) {
            int mm = mb + i;
            float e = __expf((mn - v[i]) * inv);
            ss = fmaf(e, s4v[mm], ss);
            sc = fmaf(e, c4v[mm], sc);
        }
        ss += __shfl_xor(ss, 1, 64); ss += __shfl_xor(ss, 2, 64);
        sc += __shfl_xor(sc, 1, 64); sc += __shfl_xor(sc, 2, 64);
        if (sub == 0) ang_out[l0 + r] = atan2f(ss, sc);
    }
}

// Stage 2: coalesced block-local correction scan (64 blocks x 256 thr x 4 elem).
__global__ __launch_bounds__(256) void v10_scan_local(const float* __restrict__ ang,
                                                      int* __restrict__ klocal,
                                                      int* __restrict__ bsum) {
    __shared__ int wtot[4];
    const int t = threadIdx.x;
    const int b = blockIdx.x;
    const int e = b * 256 + t;
    const int i4 = e * 4;

    float4 a = *(const float4*)(ang + i4);
    float prev = (i4 == 0) ? 0.0f : ang[i4 - 1];

    int s0 = CORR(a.x - prev);
    int s1 = CORR(a.y - a.x);
    int s2 = CORR(a.z - a.y);
    int s3 = CORR(a.w - a.z);
    int k0 = s0, k1 = k0 + s1, k2 = k1 + s2, k3 = k2 + s3;

    const int lane = t & 63, wv = t >> 6;
    int scan = k3;
    #pragma unroll
    for (int off = 1; off < 64; off <<= 1) {
        int v = __shfl_up(scan, off, 64);
        if (lane >= off) scan += v;
    }
    if (lane == 63) wtot[wv] = scan;
    __syncthreads();
    int woff = 0;
    #pragma unroll
    for (int j = 0; j < 3; ++j) if (j < wv) woff += wtot[j];
    const int excl = woff + scan - k3;

    ((int4*)klocal)[e] = make_int4(excl + k0, excl + k1, excl + k2, excl + k3);
    if (t == 255) bsum[b] = woff + scan;
}

// Stage 3: k = klocal + chunk offset; ph=(ang+2pi k)/4;
// d_out: [0,L) = real(x*exp(i*ph)), [L,2L) = ph.
__global__ __launch_bounds__(512) void v10_stage_out(const float* __restrict__ xr,
                                                     const float* __restrict__ xi,
                                                     const float* __restrict__ ang,
                                                     const int* __restrict__ klocal,
                                                     const int* __restrict__ bsum,
                                                     float* __restrict__ out_base) {
    __shared__ int s_boff;
    const int t = threadIdx.x;
    const int b = blockIdx.x;
    const int chunk = b >> 1;

    if (t < 64) {
        int v = (t < chunk) ? bsum[t] : 0;
        #pragma unroll
        for (int off = 1; off < 64; off <<= 1) v += __shfl_xor(v, off, 64);
        if (t == 0) s_boff = v;
    }
    __syncthreads();

    const int l = b * 512 + t;
    float ph = (ang[l] + TWO_PI_F * (float)(klocal[l] + s_boff)) * 0.25f;
    float s, c; sincosf(ph, &s, &c);
    float a = xr[l], bb = xi[l];
    out_base[l]      = a * c - bb * s;   // real(out)
    out_base[LN + l] = ph;               // ph channel
}

extern "C" void kernel_launch(void* const* d_in, const int* in_sizes, int n_in,
                              void* d_out, int out_size, void* d_ws, size_t ws_size,
                              hipStream_t stream) {
    (void)in_sizes; (void)n_in; (void)out_size; (void)ws_size;
    const float* xr   = (const float*)d_in[0];
    const float* xi   = (const float*)d_in[1];
    const float* temp = (const float*)d_in[5];

    float* ang    = (float*)d_ws;                                  // L f32
    int*   klocal = (int*)((char*)d_ws + LN * sizeof(float));      // L i32
    int*   bsum   = (int*)((char*)d_ws + 2 * LN * sizeof(float));  // 64 i32

    v10_stage_ang <<<LN / 64, 256, 0, stream>>>(xr, xi, temp, ang);
    v10_scan_local<<<64, 256, 0, stream>>>(ang, klocal, bsum);
    v10_stage_out <<<LN / 512, 512, 0, stream>>>(xr, xi, ang, klocal, bsum, (float*)d_out);
}

// Round 11
// 77.650 us; speedup vs baseline: 1.7020x; 1.1079x over previous
//
#include <hip/hip_runtime.h>

// BPS pipeline v11: v10 + LDS staging of the x halo tile (kills 96 uniform
// VMEM loads/thread -> 2 coalesced loads/block-row; phase 1 reads LDS broadcast).
// d_out = f32[2L]: [0,L) = real(x*exp(i*ph)), [L,2L) = ph = unwrap(ang)/4.

#define LN   65536
#define PI_F 3.14159265358979323846f
#define TWO_PI_F 6.2831853071795864769f

#define CORR(dd) (((dd) < -PI_F) ? 1 : (((dd) > PI_F) ? -1 : 0))

// Stage 1: per block of 64 outputs. Thread (m = t&63, seg = t>>6) owns rows
// seg*48..seg*48+47 of the 192-row (64-halo) dist tile for column m.
// dist -> P1 (prefix along l) -> box1 = P1 diff -> Q (prefix of box1) -> mvg = Q diff.
__global__ __launch_bounds__(256) void v11_stage_ang(const float* __restrict__ xr,
                                                     const float* __restrict__ xi,
                                                     const float* __restrict__ temp,
                                                     float* __restrict__ ang_out) {
    __shared__ float P1[64 * 193];   // P1[m][li] (pad 193: 2-way banks); reused as Q[m*131+j]
    __shared__ float xsr[192], xsi[192];  // staged x halo tile
    __shared__ float tot1[4][64];    // per-(seg,m) totals, pass 1 (lane-consecutive)
    __shared__ float tot2[4][64];    // pass 2
    __shared__ float s4v[64], c4v[64];

    const int t   = threadIdx.x;
    const int l0  = blockIdx.x * 64;
    const int m   = t & 63;
    const int seg = t >> 6;          // == wave id; uniform per wave

    // stage x tile (coalesced, one load per thread) + sin/cos tables
    if (t < 192) {
        int gl = l0 - 64 + t;
        bool ok = (unsigned)gl < (unsigned)LN;
        xsr[t] = ok ? xr[gl] : 0.0f;
        xsi[t] = ok ? xi[gl] : 0.0f;
    }
    if (t < 64) {
        float a4 = (float)t * (PI_F / 32.0f) - PI_F;   // 4*angles[m]
        float s, c; sincosf(a4, &s, &c);
        s4v[t] = s; c4v[t] = c;
    }
    __syncthreads();

    // ---- Phase 1: dist (separable nearest-64QAM quantization) + register prefix ----
    {
        const float am = (float)m * (PI_F / 128.0f) - (PI_F * 0.25f);
        float sm, cm; sincosf(am, &sm, &cm);
        const float SQ = 6.4807406984078602f;   // sqrt(42)
        const float cq = cm * SQ, sq = sm * SQ; // fold constellation scale into rotation
        float pr[48];
        float p = 0.0f;
        #pragma unroll
        for (int i = 0; i < 48; ++i) {
            int li = seg * 48 + i;
            float a = xsr[li], b = xsi[li];     // LDS broadcast (same addr across lanes)
            float tr = a * cq - b * sq;         // sqrt42 * Re(x e^{i angle})
            float ti = a * sq + b * cq;
            float rr = fminf(fmaxf(rintf(fmaf(tr, 0.5f, 3.5f)), 0.0f), 7.0f);
            float ri = fminf(fmaxf(rintf(fmaf(ti, 0.5f, 3.5f)), 0.0f), 7.0f);
            float dr = fmaf(-2.0f, rr, tr + 7.0f);
            float di = fmaf(-2.0f, ri, ti + 7.0f);
            float d = fmaf(dr, dr, di * di) * (1.0f / 42.0f);
            // zero-pad outside [0,L): x was staged as 0 there, but dist(0) != 0 -> mask
            d = ((unsigned)(l0 - 64 + li) < (unsigned)LN) ? d : 0.0f;
            p += d;
            pr[i] = p;
        }
        tot1[seg][m] = p;
        __syncthreads();
        float off = 0.0f;
        #pragma unroll
        for (int s = 0; s < 3; ++s) if (s < seg) off += tot1[s][m];
        #pragma unroll
        for (int i = 0; i < 48; ++i) P1[m * 193 + seg * 48 + i] = pr[i] + off;
    }
    __syncthreads();

    // ---- Phase 2: box1[li]=P1[li+32]-P1[li-33] for li=31..159 (j=li-31: 0..128),
    //      register prefix -> Q[m][j] (reuses P1 storage after all reads complete) ----
    const int jn = (seg < 3) ? 33 : 30;   // segs 0..2: 33 each, seg 3: 30 (129 total)
    const int j0 = seg * 33;
    {
        float q[33];
        float p2 = 0.0f;
        #pragma unroll
        for (int i = 0; i < 33; ++i) {
            if (i < jn) {
                int j = j0 + i;
                float hi = P1[m * 193 + 63 + j];
                float lo = (j >= 2) ? P1[m * 193 + j - 2] : 0.0f;
                p2 += hi - lo;
                q[i] = p2;
            }
        }
        tot2[seg][m] = p2;
        __syncthreads();                   // all P1 reads done; safe to overwrite as Q
        float off2 = 0.0f;
        #pragma unroll
        for (int s = 0; s < 3; ++s) if (s < seg) off2 += tot2[s][m];
        float* Q = P1;                     // Q[m][j] at m*131 + j (pad 131: 2-way banks)
        #pragma unroll
        for (int i = 0; i < 33; ++i) if (i < jn) Q[m * 131 + j0 + i] = q[i] + off2;
    }
    __syncthreads();

    // ---- Phase 3: mvg[r][mm] = Q[mm][r+65]-Q[mm][r]; row-normalize + softmin + atan2 ----
    {
        const float* Q = P1;
        const float T = temp[0];
        const int lane = t & 63;
        const int sub  = lane & 3;          // 4 lanes share one output row
        const int r    = (t >> 6) * 16 + (lane >> 2);   // 0..63
        const int mb   = sub * 16;

        float v[16];
        float rs = 0.0f, mn = 3.4e38f;
        #pragma unroll
        for (int i = 0; i < 16; ++i) {
            int mm = mb + i;
            float vv = Q[mm * 131 + r + 65] - Q[mm * 131 + r];
            v[i] = vv; rs += vv; mn = fminf(mn, vv);
        }
        rs += __shfl_xor(rs, 1, 64); rs += __shfl_xor(rs, 2, 64);
        mn = fminf(mn, __shfl_xor(mn, 1, 64)); mn = fminf(mn, __shfl_xor(mn, 2, 64));

        // softmax(-mvg_norm/T) weights exp((mn-v)/(rs*T)); denominator cancels in atan2
        float inv = 1.0f / (rs * T);
        float ss = 0.0f, sc = 0.0f;
        #pragma unroll
        for (int i = 0; i < 16; ++i) {
            int mm = mb + i;
            float e = __expf((mn - v[i]) * inv);
            ss = fmaf(e, s4v[mm], ss);
            sc = fmaf(e, c4v[mm], sc);
        }
        ss += __shfl_xor(ss, 1, 64); ss += __shfl_xor(ss, 2, 64);
        sc += __shfl_xor(sc, 1, 64); sc += __shfl_xor(sc, 2, 64);
        if (sub == 0) ang_out[l0 + r] = atan2f(ss, sc);
    }
}

// Stage 2: coalesced block-local correction scan (64 blocks x 256 thr x 4 elem).
__global__ __launch_bounds__(256) void v11_scan_local(const float* __restrict__ ang,
                                                      int* __restrict__ klocal,
                                                      int* __restrict__ bsum) {
    __shared__ int wtot[4];
    const int t = threadIdx.x;
    const int b = blockIdx.x;
    const int e = b * 256 + t;
    const int i4 = e * 4;

    float4 a = *(const float4*)(ang + i4);
    float prev = (i4 == 0) ? 0.0f : ang[i4 - 1];

    int s0 = CORR(a.x - prev);
    int s1 = CORR(a.y - a.x);
    int s2 = CORR(a.z - a.y);
    int s3 = CORR(a.w - a.z);
    int k0 = s0, k1 = k0 + s1, k2 = k1 + s2, k3 = k2 + s3;

    const int lane = t & 63, wv = t >> 6;
    int scan = k3;
    #pragma unroll
    for (int off = 1; off < 64; off <<= 1) {
        int v = __shfl_up(scan, off, 64);
        if (lane >= off) scan += v;
    }
    if (lane == 63) wtot[wv] = scan;
    __syncthreads();
    int woff = 0;
    #pragma unroll
    for (int j = 0; j < 3; ++j) if (j < wv) woff += wtot[j];
    const int excl = woff + scan - k3;

    ((int4*)klocal)[e] = make_int4(excl + k0, excl + k1, excl + k2, excl + k3);
    if (t == 255) bsum[b] = woff + scan;
}

// Stage 3: k = klocal + chunk offset; ph=(ang+2pi k)/4;
// d_out: [0,L) = real(x*exp(i*ph)), [L,2L) = ph.
__global__ __launch_bounds__(512) void v11_stage_out(const float* __restrict__ xr,
                                                     const float* __restrict__ xi,
                                                     const float* __restrict__ ang,
                                                     const int* __restrict__ klocal,
                                                     const int* __restrict__ bsum,
                                                     float* __restrict__ out_base) {
    __shared__ int s_boff;
    const int t = threadIdx.x;
    const int b = blockIdx.x;
    const int chunk = b >> 1;

    if (t < 64) {
        int v = (t < chunk) ? bsum[t] : 0;
        #pragma unroll
        for (int off = 1; off < 64; off <<= 1) v += __shfl_xor(v, off, 64);
        if (t == 0) s_boff = v;
    }
    __syncthreads();

    const int l = b * 512 + t;
    float ph = (ang[l] + TWO_PI_F * (float)(klocal[l] + s_boff)) * 0.25f;
    float s, c; sincosf(ph, &s, &c);
    float a = xr[l], bb = xi[l];
    out_base[l]      = a * c - bb * s;   // real(out)
    out_base[LN + l] = ph;               // ph channel
}

extern "C" void kernel_launch(void* const* d_in, const int* in_sizes, int n_in,
                              void* d_out, int out_size, void* d_ws, size_t ws_size,
                              hipStream_t stream) {
    (void)in_sizes; (void)n_in; (void)out_size; (void)ws_size;
    const float* xr   = (const float*)d_in[0];
    const float* xi   = (const float*)d_in[1];
    const float* temp = (const float*)d_in[5];

    float* ang    = (float*)d_ws;                                  // L f32
    int*   klocal = (int*)((char*)d_ws + LN * sizeof(float));      // L i32
    int*   bsum   = (int*)((char*)d_ws + 2 * LN * sizeof(float));  // 64 i32

    v11_stage_ang <<<LN / 64, 256, 0, stream>>>(xr, xi, temp, ang);
    v11_scan_local<<<64, 256, 0, stream>>>(ang, klocal, bsum);
    v11_stage_out <<<LN / 512, 512, 0, stream>>>(xr, xi, ang, klocal, bsum, (float*)d_out);
}